// Round 5
// baseline (460.461 us; speedup 1.0000x reference)
//
#include <hip/hip_runtime.h>
#include <stdint.h>

typedef _Float16 half8 __attribute__((ext_vector_type(8)));   // fp16 MFMA frag (4 VGPRs)
typedef __attribute__((ext_vector_type(4))) float f32x4;      // MFMA accumulator
typedef __attribute__((ext_vector_type(8))) unsigned short us8;

__device__ inline unsigned short f2h(float x) {
  _Float16 h = (_Float16)x;                 // v_cvt_f16_f32, RNE
  return __builtin_bit_cast(unsigned short, h);
}

// ---- async global->LDS, 16B per lane ----
__device__ inline void ld16(const unsigned short* g, unsigned short* l) {
  __builtin_amdgcn_global_load_lds(
      (const __attribute__((address_space(1))) unsigned int*)g,
      (__attribute__((address_space(3))) unsigned int*)l, 16, 0, 0);
}

// ---- fp32 -> fp16 cast, 8 elems/thread (whole tensor) ----
__global__ void k_cast16(const float* __restrict__ in, unsigned short* __restrict__ o, long n8) {
  long i = (long)blockIdx.x * blockDim.x + threadIdx.x;
  if (i >= n8) return;
  float4 a = ((const float4*)in)[i * 2];
  float4 b = ((const float4*)in)[i * 2 + 1];
  us8 h;
  h[0] = f2h(a.x); h[1] = f2h(a.y); h[2] = f2h(a.z); h[3] = f2h(a.w);
  h[4] = f2h(b.x); h[5] = f2h(b.y); h[6] = f2h(b.z); h[7] = f2h(b.w);
  *(us8*)(o + i * 8) = h;
}

// ---- fp32 -> fp16 cast of a K-row chunk per batch ----
__global__ void k_cast16c(const float* __restrict__ in, unsigned short* __restrict__ o,
                          int Kn, int Dn, int k0c, int Kc) {
  const long i = (long)blockIdx.x * blockDim.x + threadIdx.x;
  const long cols8 = (long)Kc * Dn / 8;
  const int b = (int)(i / cols8);
  const long j = i - (long)b * cols8;
  const float* p = in + (long)b * Kn * Dn + (long)k0c * Dn + j * 8;
  float4 a = *(const float4*)p;
  float4 c = *(const float4*)(p + 4);
  us8 h;
  h[0] = f2h(a.x); h[1] = f2h(a.y); h[2] = f2h(a.z); h[3] = f2h(a.w);
  h[4] = f2h(c.x); h[5] = f2h(c.y); h[6] = f2h(c.z); h[7] = f2h(c.w);
  *(us8*)(o + (long)b * Kc * Dn + j * 8) = h;
}

// ---- V [K x D] fp32 -> VT-chunk [D x Kc] fp16 (per batch, k-chunk) ----
__global__ void k_transpose16(const float* __restrict__ V, unsigned short* __restrict__ VT,
                              int Kn, int Dn, int k0c, int Kc) {
  __shared__ unsigned short t[64][65];
  const int b = blockIdx.z;
  const int k0 = blockIdx.x * 64, d0 = blockIdx.y * 64;
  const int c = threadIdx.x & 63, rr = threadIdx.x >> 6;
  const float* pV = V + (long)b * Kn * Dn;
  unsigned short* pT = VT + (long)b * Dn * Kc;
#pragma unroll
  for (int i = 0; i < 16; ++i) {
    int r = rr + i * 4;
    t[r][c] = f2h(pV[(long)(k0c + k0 + r) * Dn + d0 + c]);
  }
  __syncthreads();
#pragma unroll
  for (int i = 0; i < 16; ++i) {
    int r = rr + i * 4;
    pT[(long)(d0 + r) * Kc + k0 + c] = t[c][r];
  }
}

// ============================================================================
// m201-template GEMM port (plain HIP): 256x256 tile, 8 waves (2Mx4N), BK=64,
// LDS = 2 dbuf x 2 k-half x [256 rows x 32 cols] for A and B = 128 KiB.
// 4 phases per K-tile, each: {4-or-8 ds_read_b128 || 2 global_load_lds ->
// SBAR -> lgkmcnt(0) -> setprio(1) 16 MFMA setprio(0) -> [vmcnt(6)] -> SBAR}.
// Counted vmcnt (never 0 in main loop); 3 half-tiles (6 loads) in flight.
// Half-tile stream: Ak1(t+1)@ph1, Bk1(t+1)@ph2, Ak0(t+2)@ph3, Bk0(t+2)@ph4.
// T1 XCD swizzle, T2 LDS XOR swizzle (chunk ^ ((row>>1)&3), 2-way = free).
// C[M,N] (+)= A[M,Kin] * B[N,Kin]^T, fp16 in, fp32 out. STATS: q-axis
// column max/sumexp partials (16 slots).
// ============================================================================

#define SBAR() __builtin_amdgcn_s_barrier()
#define SCHED0() __builtin_amdgcn_sched_barrier(0)
#define LGKM0() do { asm volatile("s_waitcnt lgkmcnt(0)" ::: "memory"); SCHED0(); } while (0)
#define VMC(n) do { asm volatile("s_waitcnt vmcnt(" #n ")" ::: "memory"); } while (0)

template <int STATS, int ACC>
__launch_bounds__(512, 2)
__global__ void k_gemm_bt(const unsigned short* __restrict__ A,
                          const unsigned short* __restrict__ B,
                          float* __restrict__ C, float2* __restrict__ ps,
                          int N, int Kin, long sA_, long sB_, long sC_) {
  // [dbuf][k-half][256 rows * 32 cols] halves; half-tile = contiguous 16 KB
  __shared__ unsigned short sA[2][2][256 * 32];
  __shared__ unsigned short sB[2][2][256 * 32];

  const int tid = threadIdx.x;
  const int lane = tid & 63, wave = tid >> 6;
  const int wr = wave >> 2, wc = wave & 3;   // 2 x 4 wave grid; wave owns 128x64
  const int l15 = lane & 15;

  // ---- T1: bijective XCD swizzle (all grids here have nwg % 8 == 0) ----
  const int nx = gridDim.x, ny = gridDim.y;
  int wg = ((int)blockIdx.z * ny + blockIdx.y) * nx + blockIdx.x;
  const int nwg = nx * ny * (int)gridDim.z;
  wg = (wg & 7) * (nwg >> 3) + (wg >> 3);
  const int tn = wg % nx, tm = (wg / nx) % ny, b = wg / (nx * ny);

  const unsigned short* pA = A + b * sA_ + (long)tm * 256 * Kin;
  const unsigned short* pB = B + b * sB_ + (long)tn * 256 * Kin;
  float* pC = C + b * sC_;

  // ---- staging addressing: lane covers (row = tid>>2, chunk = tid&3) of a
  // 128-row half; LDS dest linear (tid*16B); global source col inverse-
  // swizzled: chunk' = chunk ^ ((row>>1)&3). (row+128 has same key.)
  const int r1 = tid >> 2;
  const int cswz = ((tid & 3) ^ ((r1 >> 1) & 3)) << 3;   // halves offset
  // half-tile (X, kh, t): rows 0-255 of X, cols t*64+kh*32 .. +31
#define STAGE(Xp, Xs, kh, t) do { \
    ld16(Xp + (long)r1 * Kin + (long)(t) * 64 + (kh) * 32 + cswz, \
         &Xs[(t) & 1][kh][tid * 8]); \
    ld16(Xp + (long)(r1 + 128) * Kin + (long)(t) * 64 + (kh) * 32 + cswz, \
         &Xs[(t) & 1][kh][4096 + tid * 8]); \
  } while (0)

  // ---- fragment ds_read: row stride 32 halves (64B); swizzled chunk ----
  const int cxl = (((lane >> 4) ^ ((l15 >> 1) & 3)) << 3);
#define FA(d, kh, m) (*(const half8*)&sA[d][kh][(wr * 128 + (m) * 16 + l15) * 32 + cxl])
#define FB(d, kh, n) (*(const half8*)&sB[d][kh][(wc * 64 + (n) * 16 + l15) * 32 + cxl])

  f32x4 acc[8][4];
#pragma unroll
  for (int i = 0; i < 8; ++i)
#pragma unroll
    for (int j = 0; j < 4; ++j)
#pragma unroll
      for (int r = 0; r < 4; ++r) acc[i][j][r] = 0.f;

  half8 aF[4], bF[4];

#define PH_AB(d, kh) \
  aF[0] = FA(d, kh, 0); aF[1] = FA(d, kh, 1); aF[2] = FA(d, kh, 2); aF[3] = FA(d, kh, 3); \
  bF[0] = FB(d, kh, 0); bF[1] = FB(d, kh, 1); bF[2] = FB(d, kh, 2); bF[3] = FB(d, kh, 3);
#define PH_A(d, kh) \
  aF[0] = FA(d, kh, 4); aF[1] = FA(d, kh, 5); aF[2] = FA(d, kh, 6); aF[3] = FA(d, kh, 7);

#define MM(mb) \
  __builtin_amdgcn_s_setprio(1); \
  acc[mb+0][0] = __builtin_amdgcn_mfma_f32_16x16x32_f16(aF[0], bF[0], acc[mb+0][0], 0, 0, 0); \
  acc[mb+0][1] = __builtin_amdgcn_mfma_f32_16x16x32_f16(aF[0], bF[1], acc[mb+0][1], 0, 0, 0); \
  acc[mb+0][2] = __builtin_amdgcn_mfma_f32_16x16x32_f16(aF[0], bF[2], acc[mb+0][2], 0, 0, 0); \
  acc[mb+0][3] = __builtin_amdgcn_mfma_f32_16x16x32_f16(aF[0], bF[3], acc[mb+0][3], 0, 0, 0); \
  acc[mb+1][0] = __builtin_amdgcn_mfma_f32_16x16x32_f16(aF[1], bF[0], acc[mb+1][0], 0, 0, 0); \
  acc[mb+1][1] = __builtin_amdgcn_mfma_f32_16x16x32_f16(aF[1], bF[1], acc[mb+1][1], 0, 0, 0); \
  acc[mb+1][2] = __builtin_amdgcn_mfma_f32_16x16x32_f16(aF[1], bF[2], acc[mb+1][2], 0, 0, 0); \
  acc[mb+1][3] = __builtin_amdgcn_mfma_f32_16x16x32_f16(aF[1], bF[3], acc[mb+1][3], 0, 0, 0); \
  acc[mb+2][0] = __builtin_amdgcn_mfma_f32_16x16x32_f16(aF[2], bF[0], acc[mb+2][0], 0, 0, 0); \
  acc[mb+2][1] = __builtin_amdgcn_mfma_f32_16x16x32_f16(aF[2], bF[1], acc[mb+2][1], 0, 0, 0); \
  acc[mb+2][2] = __builtin_amdgcn_mfma_f32_16x16x32_f16(aF[2], bF[2], acc[mb+2][2], 0, 0, 0); \
  acc[mb+2][3] = __builtin_amdgcn_mfma_f32_16x16x32_f16(aF[2], bF[3], acc[mb+2][3], 0, 0, 0); \
  acc[mb+3][0] = __builtin_amdgcn_mfma_f32_16x16x32_f16(aF[3], bF[0], acc[mb+3][0], 0, 0, 0); \
  acc[mb+3][1] = __builtin_amdgcn_mfma_f32_16x16x32_f16(aF[3], bF[1], acc[mb+3][1], 0, 0, 0); \
  acc[mb+3][2] = __builtin_amdgcn_mfma_f32_16x16x32_f16(aF[3], bF[2], acc[mb+3][2], 0, 0, 0); \
  acc[mb+3][3] = __builtin_amdgcn_mfma_f32_16x16x32_f16(aF[3], bF[3], acc[mb+3][3], 0, 0, 0); \
  __builtin_amdgcn_s_setprio(0);

  // Full group for K-tile t (stages k1(t+1) in ph1-2, k0(t+2) in ph3-4).
  // Steady state: exactly 3 half-tiles (6 loads) outstanding at each VMC(6).
#define GROUP_FULL(t) do { \
    const int d_ = (t) & 1; \
    PH_AB(d_, 0); STAGE(pA, sA, 1, (t) + 1); SBAR(); LGKM0(); MM(0) SBAR(); \
    PH_A(d_, 0);  STAGE(pB, sB, 1, (t) + 1); SBAR(); LGKM0(); MM(4) VMC(6); SBAR(); \
    PH_AB(d_, 1); STAGE(pA, sA, 0, (t) + 2); SBAR(); LGKM0(); MM(0) SBAR(); \
    PH_A(d_, 1);  STAGE(pB, sB, 0, (t) + 2); SBAR(); LGKM0(); MM(4) VMC(6); SBAR(); \
  } while (0)

  const int nt = Kin >> 6;   // BK=64 tiles (nt >= 2)

  // prologue: half-tile stream positions 1..6 = k0(0), k1(0), k0(1);
  // VMC(8) lands the first 4 loads = k0(0) complete (k1(0) covered by
  // G0.ph2's VMC(6), which lands through Ak0(1)).
  STAGE(pA, sA, 0, 0); STAGE(pB, sB, 0, 0);
  STAGE(pA, sA, 1, 0); STAGE(pB, sB, 1, 0);
  STAGE(pA, sA, 0, 1); STAGE(pB, sB, 0, 1);
  VMC(8); SBAR();

  for (int t = 0; t + 2 < nt; ++t) GROUP_FULL(t);

  // penultimate group (t = nt-2): stages only k1(nt-1); drain 6 -> 4
  {
    const int d_ = (nt - 2) & 1;
    PH_AB(d_, 0); STAGE(pA, sA, 1, nt - 1); SBAR(); LGKM0(); MM(0) SBAR();
    PH_A(d_, 0);  STAGE(pB, sB, 1, nt - 1); SBAR(); LGKM0(); MM(4) VMC(6); SBAR();
    PH_AB(d_, 1);                           SBAR(); LGKM0(); MM(0) SBAR();
    PH_A(d_, 1);                            SBAR(); LGKM0(); MM(4) VMC(4); SBAR();
  }
  // last group (t = nt-1): no stages; drain 4 -> 0 at ph2
  {
    const int d_ = (nt - 1) & 1;
    PH_AB(d_, 0); SBAR(); LGKM0(); MM(0) SBAR();
    PH_A(d_, 0);  SBAR(); LGKM0(); MM(4) VMC(0); SBAR();
    PH_AB(d_, 1); SBAR(); LGKM0(); MM(0) SBAR();
    PH_A(d_, 1);  SBAR(); LGKM0(); MM(4)
  }

  // ---- epilogue: C write (C/D layout: col=lane&15, row=(lane>>4)*4+r) ----
  const int crow0 = tm * 256 + wr * 128 + (lane >> 4) * 4;
  const int ccol0 = tn * 256 + wc * 64 + l15;
#pragma unroll
  for (int m = 0; m < 8; ++m)
#pragma unroll
    for (int n = 0; n < 4; ++n)
#pragma unroll
      for (int r = 0; r < 4; ++r) {
        long idx = (long)(crow0 + m * 16 + r) * N + ccol0 + n * 16;
        if constexpr (ACC) pC[idx] += acc[m][n][r];
        else pC[idx] = acc[m][n][r];
      }

  if constexpr (STATS) {
    // per-wave column stats over this wave's 128 rows; 16 slots per (b, col)
#pragma unroll
    for (int n = 0; n < 4; ++n) {
      float mx = -3.0e38f;
#pragma unroll
      for (int m = 0; m < 8; ++m)
#pragma unroll
        for (int r = 0; r < 4; ++r) mx = fmaxf(mx, acc[m][n][r]);
      mx = fmaxf(mx, __shfl_xor(mx, 16, 64));
      mx = fmaxf(mx, __shfl_xor(mx, 32, 64));
      float l = 0.f;
#pragma unroll
      for (int m = 0; m < 8; ++m)
#pragma unroll
        for (int r = 0; r < 4; ++r) l += __expf(acc[m][n][r] - mx);
      l += __shfl_xor(l, 16, 64);
      l += __shfl_xor(l, 32, 64);
      if (lane < 16) {
        int col = tn * 256 + wc * 64 + n * 16 + lane;
        ps[((long)(b * 16 + tm * 2 + wr)) * N + col] = make_float2(mx, l);
      }
    }
  }
}

// ---- combine 16 per-tile partials -> (M_k, 1/L_k) ----
__global__ void k_stats_combine(const float2* __restrict__ ps, float2* __restrict__ st, int Kc) {
  const long i = (long)blockIdx.x * blockDim.x + threadIdx.x;  // over 8*Kc
  const int b = (int)(i / Kc), k = (int)(i % Kc);
  float M = -3.0e38f;
#pragma unroll
  for (int j = 0; j < 16; ++j) M = fmaxf(M, ps[((long)(b * 16 + j)) * Kc + k].x);
  float L = 0.f;
#pragma unroll
  for (int j = 0; j < 16; ++j) {
    float2 v = ps[((long)(b * 16 + j)) * Kc + k];
    L += v.y * __expf(v.x - M);
  }
  st[i] = make_float2(M, 1.0f / L);
}

// ---- P = exp(S - M_k) * invL_k -> fp16, 8 elems/thread (chunk) ----
__global__ void k_pcomp(const float* __restrict__ S, const float2* __restrict__ st,
                        unsigned short* __restrict__ P, int Kc) {
  const long i = (long)blockIdx.x * blockDim.x + threadIdx.x;
  const int kw = Kc >> 3;              // threads per row
  const long r = i / kw;               // row = b*2048 + q
  const int kb = (int)(i - r * kw) * 8;
  const int b = (int)(r >> 11);
  const float* sp = S + r * Kc + kb;
  float4 s0 = *(const float4*)sp;
  float4 s1 = *(const float4*)(sp + 4);
  const float2* tp = st + (long)b * Kc + kb;
  us8 o;
  float sv[8] = {s0.x, s0.y, s0.z, s0.w, s1.x, s1.y, s1.z, s1.w};
#pragma unroll
  for (int j = 0; j < 8; ++j) {
    float2 t = tp[j];
    o[j] = f2h(__expf(sv[j] - t.x) * t.y);
  }
  *(us8*)(P + r * Kc + kb) = o;
}

extern "C" void kernel_launch(void* const* d_in, const int* in_sizes, int n_in,
                              void* d_out, int out_size, void* d_ws, size_t ws_size,
                              hipStream_t stream) {
  const float* Q = (const float*)d_in[0];
  const float* Kp = (const float*)d_in[1];
  const float* V = (const float*)d_in[2];
  float* out = (float*)d_out;

  constexpr int Bb = 8, Qn = 2048, Kn = 2048, Dn = 1024;
  constexpr long QD = (long)Qn * Dn;

  // ---- tiered k-chunk size (full-GPU grids preferred) ----
  long Kc = 1024;
  for (;;) {
    size_t uKP = (size_t)Bb * Qn * Kc * 2;        // P (>= k16-chunk size)
    size_t need = (size_t)Bb * QD * 2              // q16
                + uKP                              // union(k16-chunk, P)
                + (size_t)Bb * Dn * Kc * 2         // vt chunk
                + (size_t)Bb * Qn * Kc * 4         // S chunk
                + (size_t)Bb * 16 * Kc * 8         // partial stats
                + (size_t)Bb * Kc * 8;             // final stats
    if (need <= ws_size || Kc == 256) break;
    Kc >>= 1;
  }
  const int nc = Kn / (int)Kc;

  char* w = (char*)d_ws;
  unsigned short* q16 = (unsigned short*)w; w += (size_t)Bb * QD * 2;
  unsigned short* kp  = (unsigned short*)w; w += (size_t)Bb * Qn * Kc * 2;  // k16c & P
  unsigned short* vt  = (unsigned short*)w; w += (size_t)Bb * Dn * Kc * 2;
  float* S            = (float*)w;          w += (size_t)Bb * Qn * Kc * 4;
  float2* ps          = (float2*)w;         w += (size_t)Bb * 16 * Kc * 8;
  float2* st          = (float2*)w;

  unsigned short* k16c = kp;   // alias: k16c dead before P is written
  unsigned short* P    = kp;

  // Q -> fp16 once
  k_cast16<<<(int)(Bb * QD / 8 / 256), 256, 0, stream>>>(Q, q16, Bb * QD / 8);

  for (int c = 0; c < nc; ++c) {
    const int k0c = c * (int)Kc;
    // K-chunk -> fp16 ; V-chunk -> VT fp16
    k_cast16c<<<(int)((long)Bb * Kc * Dn / 8 / 256), 256, 0, stream>>>(
        Kp, k16c, Kn, Dn, k0c, (int)Kc);
    k_transpose16<<<dim3((int)Kc / 64, Dn / 64, Bb), 256, 0, stream>>>(
        V, vt, Kn, Dn, k0c, (int)Kc);
    // S[:, :, chunk] = Q @ K_chunk^T  (+ column stats over q)
    k_gemm_bt<1, 0><<<dim3((int)Kc / 256, Qn / 256, Bb), 512, 0, stream>>>(
        q16, k16c, S, ps, (int)Kc, Dn, QD, (long)Kc * Dn, (long)Qn * Kc);
    k_stats_combine<<<Bb * (int)Kc / 256, 256, 0, stream>>>(ps, st, (int)Kc);
    // P = exp(S - M) * invL  (fp16, overwrites k16c slot)
    k_pcomp<<<(int)((long)Bb * Qn * (Kc / 8) / 256), 256, 0, stream>>>(
        S, st, P, (int)Kc);
    // out (+)= P_chunk @ V_chunk
    if (c == 0)
      k_gemm_bt<0, 0><<<dim3(Dn / 256, Qn / 256, Bb), 512, 0, stream>>>(
          P, vt, out, nullptr, Dn, (int)Kc, (long)Qn * Kc, (long)Dn * Kc, QD);
    else
      k_gemm_bt<0, 1><<<dim3(Dn / 256, Qn / 256, Bb), 512, 0, stream>>>(
          P, vt, out, nullptr, Dn, (int)Kc, (long)Qn * Kc, (long)Dn * Kc, QD);
  }
}